// Round 1
// baseline (1055.736 us; speedup 1.0000x reference)
//
#include <hip/hip_runtime.h>

// ---------------- problem constants ----------------
#define N_NODES 30000
#define N_EDGES 480000
#define E_TOT   510000        // edges + self loops
#define BQ      4096
#define IN_DIM  1281
#define KP1     1312          // 1281 padded to mult of 32
#define MP      30080         // 30000 padded to mult of 128

typedef __attribute__((ext_vector_type(8))) short bf16x8;
typedef __attribute__((ext_vector_type(4))) float f32x4;

__device__ __forceinline__ short f2bf(float f) {
    unsigned int u = __builtin_bit_cast(unsigned int, f);
    u += 0x7fffu + ((u >> 16) & 1u);       // RNE
    return (short)(u >> 16);
}

__device__ __forceinline__ void async16(void* lds, const void* g) {
    __builtin_amdgcn_global_load_lds(
        (const __attribute__((address_space(1))) void*)g,
        (__attribute__((address_space(3))) void*)lds, 16, 0, 0);
}

__device__ __forceinline__ float elu1(float x) {
    return x > 0.f ? x : __expf(x) - 1.f;
}

// ---------------- pack kernels ----------------
// x (30000x1281 f32) -> A (30080x1312 bf16), zero padded
__global__ __launch_bounds__(256) void pack_x_kernel(const float* __restrict__ x,
                                                     short* __restrict__ A) {
    int idx = blockIdx.x * 256 + threadIdx.x;      // one per 8 elements
    const int perRow = KP1 / 8;                    // 164
    int m = idx / perRow;
    int t = idx - m * perRow;
    if (m >= MP) return;
    int k0 = t * 8;
    bf16x8 v;
    if (m < N_NODES) {
        const float* xr = x + (size_t)m * IN_DIM;
        #pragma unroll
        for (int j = 0; j < 8; ++j) {
            int k = k0 + j;
            v[j] = (k < IN_DIM) ? f2bf(xr[k]) : (short)0;
        }
    } else {
        #pragma unroll
        for (int j = 0; j < 8; ++j) v[j] = (short)0;
    }
    *(bf16x8*)(A + (size_t)m * KP1 + k0) = v;
}

// [Wl|Wr] (K x 256 each, row-major) -> Bt (512 x Kp bf16, N-major = B^T layout)
__global__ __launch_bounds__(256) void pack_w_kernel(const float* __restrict__ Wl,
                                                     const float* __restrict__ Wr,
                                                     short* __restrict__ Bt, int K, int Kp) {
    int idx = blockIdx.x * 256 + threadIdx.x;
    int perRow = Kp / 8;
    int n = idx / perRow;
    int t = idx - n * perRow;
    if (n >= 512) return;
    const float* W = (n < 256) ? Wl : Wr;
    int nc = n & 255;
    int k0 = t * 8;
    bf16x8 v;
    #pragma unroll
    for (int j = 0; j < 8; ++j) {
        int k = k0 + j;
        v[j] = (k < K) ? f2bf(W[(size_t)k * 256 + nc]) : (short)0;
    }
    *(bf16x8*)(Bt + (size_t)n * Kp + k0) = v;
}

// ---------------- bf16 MFMA GEMM (m97 structure) ----------------
// C(M x 512) = A(MP x Kp) * Bt(512 x Kp)^T + bias ; 128x128 tile, 4 waves of 64x64
__global__ __launch_bounds__(256) void gemm_bf16_kernel(
    const short* __restrict__ A, const short* __restrict__ B,
    float* __restrict__ C,
    const float* __restrict__ biasLo, const float* __restrict__ biasHi,
    int Mstore, int Kp)
{
    __shared__ short As[128 * 32];
    __shared__ short Bs[128 * 32];
    const int tid  = threadIdx.x;
    const int wave = tid >> 6;
    const int lane = tid & 63;
    const int l15  = lane & 15;
    const int quad = lane >> 4;
    const int bm = blockIdx.x * 128;
    const int bn = blockIdx.y * 128;

    f32x4 acc[4][4] = {};

    // staging: each glds call = 16 rows x 64B; wave w covers rows 32w..32w+31 (2 calls each for A,B)
    const int srow = wave * 32 + (lane >> 2);
    const int scol = (lane & 3) * 8;
    const short* Ag0 = A + (size_t)(bm + srow) * Kp + scol;
    const short* Ag1 = Ag0 + (size_t)16 * Kp;
    const short* Bg0 = B + (size_t)(bn + srow) * Kp + scol;
    const short* Bg1 = Bg0 + (size_t)16 * Kp;
    short* As0 = &As[(wave * 32) * 32];
    short* As1 = &As[(wave * 32 + 16) * 32];
    short* Bs0 = &Bs[(wave * 32) * 32];
    short* Bs1 = &Bs[(wave * 32 + 16) * 32];

    const int wm = (wave & 1) * 64;
    const int wn = (wave >> 1) * 64;

    for (int kk = 0; kk < Kp; kk += 32) {
        async16(As0, Ag0 + kk);
        async16(As1, Ag1 + kk);
        async16(Bs0, Bg0 + kk);
        async16(Bs1, Bg1 + kk);
        __syncthreads();   // compiler emits vmcnt(0) drain before barrier

        bf16x8 af[4], bfr[4];
        #pragma unroll
        for (int i = 0; i < 4; ++i)
            af[i] = *(const bf16x8*)&As[(wm + i * 16 + l15) * 32 + quad * 8];
        #pragma unroll
        for (int i = 0; i < 4; ++i)
            bfr[i] = *(const bf16x8*)&Bs[(wn + i * 16 + l15) * 32 + quad * 8];
        #pragma unroll
        for (int mi = 0; mi < 4; ++mi)
            #pragma unroll
            for (int ni = 0; ni < 4; ++ni)
                acc[mi][ni] = __builtin_amdgcn_mfma_f32_16x16x32_bf16(
                    af[mi], bfr[ni], acc[mi][ni], 0, 0, 0);
        __syncthreads();
    }

    // C/D layout: col = lane&15, row = quad*4 + reg  [measured m89/m91]
    #pragma unroll
    for (int mi = 0; mi < 4; ++mi) {
        int row = bm + wm + mi * 16 + quad * 4;
        #pragma unroll
        for (int ni = 0; ni < 4; ++ni) {
            int col = bn + wn + ni * 16 + l15;
            float bv = (col < 256) ? biasLo[col] : biasHi[col - 256];
            #pragma unroll
            for (int r = 0; r < 4; ++r) {
                int rr = row + r;
                if (rr < Mstore)
                    C[(size_t)rr * 512 + col] = acc[mi][ni][r] + bv;
            }
        }
    }
}

// ---------------- CSR build (grouped by dst) ----------------
__global__ __launch_bounds__(256) void edge_count_kernel(const int* __restrict__ ei,
                                                         int* __restrict__ counts) {
    int e = blockIdx.x * 256 + threadIdx.x;
    if (e >= E_TOT) return;
    int dst = (e < N_EDGES) ? ei[N_EDGES + e] : (e - N_EDGES);
    atomicAdd(&counts[dst], 1);
}

__global__ __launch_bounds__(1024) void scan_kernel(const int* __restrict__ counts,
                                                    int* __restrict__ offs,
                                                    int* __restrict__ cursor) {
    __shared__ int buf[1024];
    __shared__ int carryS;
    if (threadIdx.x == 0) carryS = 0;
    __syncthreads();
    for (int base = 0; base < N_NODES; base += 1024) {
        int i = base + (int)threadIdx.x;
        int v = (i < N_NODES) ? counts[i] : 0;
        buf[threadIdx.x] = v;
        __syncthreads();
        for (int off = 1; off < 1024; off <<= 1) {
            int t = (threadIdx.x >= (unsigned)off) ? buf[threadIdx.x - off] : 0;
            __syncthreads();
            buf[threadIdx.x] += t;
            __syncthreads();
        }
        int incl = buf[threadIdx.x];
        int carry = carryS;
        if (i < N_NODES) {
            int exc = carry + incl - v;
            offs[i] = exc;
            cursor[i] = exc;
        }
        __syncthreads();
        if (threadIdx.x == 1023) carryS = carry + incl;
        __syncthreads();
    }
    if (threadIdx.x == 0) offs[N_NODES] = carryS;
}

__global__ __launch_bounds__(256) void edge_scatter_kernel(const int* __restrict__ ei,
                                                           int* __restrict__ cursor,
                                                           int* __restrict__ eidx) {
    int e = blockIdx.x * 256 + threadIdx.x;
    if (e >= E_TOT) return;
    int dst = (e < N_EDGES) ? ei[N_EDGES + e] : (e - N_EDGES);
    int pos = atomicAdd(&cursor[dst], 1);
    eidx[pos] = e;
}

// ---------------- layer-1 edge logits (4 heads x 64) ----------------
__global__ __launch_bounds__(256) void edge_logits1_kernel(
    const int* __restrict__ ei, const float* __restrict__ C1,
    const float* __restrict__ att, float* __restrict__ logits)
{
    int wid = (int)((blockIdx.x * 256 + threadIdx.x) >> 6);
    int lane = threadIdx.x & 63;
    if (wid >= E_TOT) return;
    int e = wid, src, dst;
    if (e < N_EDGES) { src = ei[e]; dst = ei[N_EDGES + e]; }
    else { src = e - N_EDGES; dst = src; }
    const float* xl = C1 + (size_t)src * 512;        // cols 0..255  = Wl out
    const float* xr = C1 + (size_t)dst * 512 + 256;  // cols 256..511 = Wr out
    float p0, p1, p2, p3, v;
    v = xl[lane]       + xr[lane];       v = v > 0.f ? v : 0.2f * v; p0 = v * att[lane];
    v = xl[64 + lane]  + xr[64 + lane];  v = v > 0.f ? v : 0.2f * v; p1 = v * att[64 + lane];
    v = xl[128 + lane] + xr[128 + lane]; v = v > 0.f ? v : 0.2f * v; p2 = v * att[128 + lane];
    v = xl[192 + lane] + xr[192 + lane]; v = v > 0.f ? v : 0.2f * v; p3 = v * att[192 + lane];
    #pragma unroll
    for (int off = 32; off > 0; off >>= 1) {
        p0 += __shfl_xor(p0, off, 64);
        p1 += __shfl_xor(p1, off, 64);
        p2 += __shfl_xor(p2, off, 64);
        p3 += __shfl_xor(p3, off, 64);
    }
    if (lane == 0) {
        float4 o; o.x = p0; o.y = p1; o.z = p2; o.w = p3;
        *(float4*)(logits + (size_t)e * 4) = o;
    }
}

// ---------------- layer-1 per-node aggregate + bias + elu -> h1 bf16 ----------------
__global__ __launch_bounds__(256) void node_aggr1_kernel(
    const int* __restrict__ ei, const int* __restrict__ offs,
    const int* __restrict__ eidx, const float* __restrict__ C1,
    const float* __restrict__ logits, const float* __restrict__ bias,
    short* __restrict__ h1b)
{
    int wid = (int)((blockIdx.x * 256 + threadIdx.x) >> 6);
    int lane = threadIdx.x & 63;
    if (wid >= N_NODES) return;
    int n = wid;
    int beg = offs[n], end = offs[n + 1];
    float m0 = -1e30f, m1 = -1e30f, m2 = -1e30f, m3 = -1e30f;
    for (int i = beg + lane; i < end; i += 64) {
        float4 lg = *(const float4*)(logits + (size_t)eidx[i] * 4);
        m0 = fmaxf(m0, lg.x); m1 = fmaxf(m1, lg.y);
        m2 = fmaxf(m2, lg.z); m3 = fmaxf(m3, lg.w);
    }
    #pragma unroll
    for (int off = 32; off > 0; off >>= 1) {
        m0 = fmaxf(m0, __shfl_xor(m0, off, 64));
        m1 = fmaxf(m1, __shfl_xor(m1, off, 64));
        m2 = fmaxf(m2, __shfl_xor(m2, off, 64));
        m3 = fmaxf(m3, __shfl_xor(m3, off, 64));
    }
    float a0 = 0.f, a1 = 0.f, a2 = 0.f, a3 = 0.f;
    float d0 = 0.f, d1 = 0.f, d2 = 0.f, d3 = 0.f;
    for (int i = beg; i < end; ++i) {
        int e = eidx[i];
        int src = (e < N_EDGES) ? ei[e] : (e - N_EDGES);
        float4 lg = *(const float4*)(logits + (size_t)e * 4);
        float e0 = __expf(lg.x - m0), e1 = __expf(lg.y - m1);
        float e2 = __expf(lg.z - m2), e3 = __expf(lg.w - m3);
        d0 += e0; d1 += e1; d2 += e2; d3 += e3;
        const float* xl = C1 + (size_t)src * 512;
        a0 += e0 * xl[lane];
        a1 += e1 * xl[64 + lane];
        a2 += e2 * xl[128 + lane];
        a3 += e3 * xl[192 + lane];
    }
    size_t base = (size_t)n * 256;
    h1b[base + lane]       = f2bf(elu1(a0 / (d0 + 1e-16f) + bias[lane]));
    h1b[base + 64 + lane]  = f2bf(elu1(a1 / (d1 + 1e-16f) + bias[64 + lane]));
    h1b[base + 128 + lane] = f2bf(elu1(a2 / (d2 + 1e-16f) + bias[128 + lane]));
    h1b[base + 192 + lane] = f2bf(elu1(a3 / (d3 + 1e-16f) + bias[192 + lane]));
}

// ---------------- layer-2 edge logits (1 head x 256) ----------------
__global__ __launch_bounds__(256) void edge_logits2_kernel(
    const int* __restrict__ ei, const float* __restrict__ C2,
    const float* __restrict__ att, float* __restrict__ logits)
{
    int wid = (int)((blockIdx.x * 256 + threadIdx.x) >> 6);
    int lane = threadIdx.x & 63;
    if (wid >= E_TOT) return;
    int e = wid, src, dst;
    if (e < N_EDGES) { src = ei[e]; dst = ei[N_EDGES + e]; }
    else { src = e - N_EDGES; dst = src; }
    const float* xl = C2 + (size_t)src * 512;
    const float* xr = C2 + (size_t)dst * 512 + 256;
    float p = 0.f;
    #pragma unroll
    for (int r = 0; r < 4; ++r) {
        int j = r * 64 + lane;
        float v = xl[j] + xr[j];
        v = v > 0.f ? v : 0.2f * v;
        p += v * att[j];
    }
    #pragma unroll
    for (int off = 32; off > 0; off >>= 1) p += __shfl_xor(p, off, 64);
    if (lane == 0) logits[e] = p;
}

// ---------------- layer-2 per-node aggregate + bias + elu -> h2 f32 ----------------
__global__ __launch_bounds__(256) void node_aggr2_kernel(
    const int* __restrict__ ei, const int* __restrict__ offs,
    const int* __restrict__ eidx, const float* __restrict__ C2,
    const float* __restrict__ logits, const float* __restrict__ bias,
    float* __restrict__ h2)
{
    int wid = (int)((blockIdx.x * 256 + threadIdx.x) >> 6);
    int lane = threadIdx.x & 63;
    if (wid >= N_NODES) return;
    int n = wid;
    int beg = offs[n], end = offs[n + 1];
    float m = -1e30f;
    for (int i = beg + lane; i < end; i += 64) m = fmaxf(m, logits[eidx[i]]);
    #pragma unroll
    for (int off = 32; off > 0; off >>= 1) m = fmaxf(m, __shfl_xor(m, off, 64));
    float a0 = 0.f, a1 = 0.f, a2 = 0.f, a3 = 0.f, d = 0.f;
    for (int i = beg; i < end; ++i) {
        int e = eidx[i];
        int src = (e < N_EDGES) ? ei[e] : (e - N_EDGES);
        float ex = __expf(logits[e] - m);
        d += ex;
        const float* xl = C2 + (size_t)src * 512;
        a0 += ex * xl[lane];
        a1 += ex * xl[64 + lane];
        a2 += ex * xl[128 + lane];
        a3 += ex * xl[192 + lane];
    }
    float inv = 1.f / (d + 1e-16f);
    size_t base = (size_t)n * 256;
    h2[base + lane]       = elu1(a0 * inv + bias[lane]);
    h2[base + 64 + lane]  = elu1(a1 * inv + bias[64 + lane]);
    h2[base + 128 + lane] = elu1(a2 * inv + bias[128 + lane]);
    h2[base + 192 + lane] = elu1(a3 * inv + bias[192 + lane]);
}

// ---------------- MLP head: one block (128 thr) per batch row ----------------
__global__ __launch_bounds__(128) void head_mlp_kernel(
    const float* __restrict__ h2, const int* __restrict__ sel,
    const float* __restrict__ wt, const float* __restrict__ mut,
    const float* __restrict__ W1, const float* __restrict__ b1,
    const float* __restrict__ W2, const float* __restrict__ b2,
    const float* __restrict__ W3, const float* __restrict__ b3,
    float* __restrict__ out)
{
    __shared__ float comb[296];
    __shared__ float z1[128];
    int b = blockIdx.x;
    int t = threadIdx.x;
    const float* hrow = h2 + (size_t)sel[b] * 256;
    comb[t] = hrow[t];
    comb[128 + t] = hrow[128 + t];
    if (t < 40) comb[256 + t] = (t < 20) ? wt[b * 20 + t] : mut[b * 20 + t - 20];
    __syncthreads();
    float s = b1[t];
    #pragma unroll 8
    for (int i = 0; i < 296; ++i) s += comb[i] * W1[i * 128 + t];
    z1[t] = fmaxf(s, 0.f);
    __syncthreads();
    if (t < 64) {
        float s2 = b2[t];
        #pragma unroll 8
        for (int i = 0; i < 128; ++i) s2 += z1[i] * W2[i * 64 + t];
        float v = fmaxf(s2, 0.f) * W3[t];
        #pragma unroll
        for (int off = 32; off > 0; off >>= 1) v += __shfl_xor(v, off, 64);
        if (t == 0) out[b] = v + b3[0];
    }
}

// ---------------- launch ----------------
extern "C" void kernel_launch(void* const* d_in, const int* in_sizes, int n_in,
                              void* d_out, int out_size, void* d_ws, size_t ws_size,
                              hipStream_t stream) {
    const float* x     = (const float*)d_in[0];
    const int*   ei    = (const int*)  d_in[1];
    const int*   sel   = (const int*)  d_in[2];
    const float* wt    = (const float*)d_in[3];
    const float* mut   = (const float*)d_in[4];
    const float* Wl1   = (const float*)d_in[5];
    const float* bl1   = (const float*)d_in[6];
    const float* Wr1   = (const float*)d_in[7];
    const float* br1   = (const float*)d_in[8];
    const float* att1  = (const float*)d_in[9];
    const float* bias1 = (const float*)d_in[10];
    const float* Wl2   = (const float*)d_in[11];
    const float* bl2   = (const float*)d_in[12];
    const float* Wr2   = (const float*)d_in[13];
    const float* br2   = (const float*)d_in[14];
    const float* att2  = (const float*)d_in[15];
    const float* bias2 = (const float*)d_in[16];
    const float* hW1   = (const float*)d_in[17];
    const float* hb1   = (const float*)d_in[18];
    const float* hW2   = (const float*)d_in[19];
    const float* hb2   = (const float*)d_in[20];
    const float* hW3   = (const float*)d_in[21];
    const float* hb3   = (const float*)d_in[22];
    float* out = (float*)d_out;

    // workspace layout (~168 MB, 256B-aligned chunks)
    char* w = (char*)d_ws;
    size_t off = 0;
    auto alloc = [&](size_t bytes) -> void* {
        void* p = w + off;
        off += (bytes + 255) & ~(size_t)255;
        return p;
    };
    short* Abf    = (short*)alloc((size_t)MP * KP1 * 2);        // x bf16; later reused as C2
    short* Wbf    = (short*)alloc((size_t)512 * KP1 * 2);       // [Wl1|Wr1]^T bf16
    float* C1     = (float*)alloc((size_t)N_NODES * 512 * 4);   // [xl1|xr1]; later reused as h2
    float* logits = (float*)alloc((size_t)E_TOT * 4 * 4);       // L1: E x 4; L2 reuses as E x 1
    int*   counts = (int*)  alloc((size_t)N_NODES * 4);
    int*   cursor = (int*)  alloc((size_t)N_NODES * 4);
    int*   offs   = (int*)  alloc((size_t)(N_NODES + 1) * 4);
    int*   eidx   = (int*)  alloc((size_t)E_TOT * 4);
    short* H1bf   = (short*)alloc((size_t)MP * 256 * 2);        // h1 bf16 (GEMM2 A)
    short* W2bf   = (short*)alloc((size_t)512 * 256 * 2);       // [Wl2|Wr2]^T bf16
    float* C2 = (float*)Abf;   // [xl2|xr2] overlays dead x-bf16
    float* h2 = C1;            // h2 overlays dead C1
    (void)in_sizes; (void)n_in; (void)out_size; (void)ws_size;

    hipMemsetAsync(counts, 0, (size_t)N_NODES * 4, stream);

    // pack inputs to bf16
    pack_x_kernel<<<(MP * (KP1 / 8)) / 256, 256, 0, stream>>>(x, Abf);
    pack_w_kernel<<<(512 * (KP1 / 8) + 255) / 256, 256, 0, stream>>>(Wl1, Wr1, Wbf, IN_DIM, KP1);
    pack_w_kernel<<<(512 * (256 / 8) + 255) / 256, 256, 0, stream>>>(Wl2, Wr2, W2bf, 256, 256);

    // CSR by dst (shared by both layers)
    edge_count_kernel<<<(E_TOT + 255) / 256, 256, 0, stream>>>(ei, counts);
    scan_kernel<<<1, 1024, 0, stream>>>(counts, offs, cursor);
    edge_scatter_kernel<<<(E_TOT + 255) / 256, 256, 0, stream>>>(ei, cursor, eidx);

    dim3 gemm_grid(MP / 128, 4);
    // layer 1
    gemm_bf16_kernel<<<gemm_grid, 256, 0, stream>>>(Abf, Wbf, C1, bl1, br1, N_NODES, KP1);
    edge_logits1_kernel<<<(E_TOT + 3) / 4, 256, 0, stream>>>(ei, C1, att1, logits);
    node_aggr1_kernel<<<(N_NODES + 3) / 4, 256, 0, stream>>>(ei, offs, eidx, C1, logits, bias1, H1bf);
    // layer 2
    gemm_bf16_kernel<<<gemm_grid, 256, 0, stream>>>(H1bf, W2bf, C2, bl2, br2, N_NODES, 256);
    edge_logits2_kernel<<<(E_TOT + 3) / 4, 256, 0, stream>>>(ei, C2, att2, logits);
    node_aggr2_kernel<<<(N_NODES + 3) / 4, 256, 0, stream>>>(ei, offs, eidx, C2, logits, bias2, h2);
    // head
    head_mlp_kernel<<<BQ, 128, 0, stream>>>(h2, sel, wt, mut, hW1, hb1, hW2, hb2, hW3, hb3, out);
}

// Round 2
// 720.593 us; speedup vs baseline: 1.4651x; 1.4651x over previous
//
#include <hip/hip_runtime.h>

// ---------------- problem constants ----------------
#define N_NODES 30000
#define N_EDGES 480000
#define E_TOT   510000        // edges + self loops
#define BQ      4096
#define IN_DIM  1281
#define KP1     1312          // 1281 padded to mult of 32
#define MP      30080         // 30000 padded to mult of 128

typedef __attribute__((ext_vector_type(8))) short bf16x8;
typedef __attribute__((ext_vector_type(4))) short short4v;
typedef __attribute__((ext_vector_type(4))) float f32x4;

__device__ __forceinline__ short f2bf(float f) {
    unsigned int u = __builtin_bit_cast(unsigned int, f);
    u += 0x7fffu + ((u >> 16) & 1u);       // RNE
    return (short)(u >> 16);
}

__device__ __forceinline__ float bf2f(short s) {
    unsigned int u = ((unsigned int)(unsigned short)s) << 16;
    return __builtin_bit_cast(float, u);
}

__device__ __forceinline__ void async16(void* lds, const void* g) {
    __builtin_amdgcn_global_load_lds(
        (const __attribute__((address_space(1))) void*)g,
        (__attribute__((address_space(3))) void*)lds, 16, 0, 0);
}

__device__ __forceinline__ float elu1(float x) {
    return x > 0.f ? x : __expf(x) - 1.f;
}

__device__ __forceinline__ float lrelu(float x) {
    return x > 0.f ? x : 0.2f * x;
}

// ---------------- pack kernels ----------------
// x (30000x1281 f32) -> A (30080x1312 bf16), zero padded
__global__ __launch_bounds__(256) void pack_x_kernel(const float* __restrict__ x,
                                                     short* __restrict__ A) {
    int idx = blockIdx.x * 256 + threadIdx.x;      // one per 8 elements
    const int perRow = KP1 / 8;                    // 164
    int m = idx / perRow;
    int t = idx - m * perRow;
    if (m >= MP) return;
    int k0 = t * 8;
    bf16x8 v;
    if (m < N_NODES) {
        const float* xr = x + (size_t)m * IN_DIM;
        #pragma unroll
        for (int j = 0; j < 8; ++j) {
            int k = k0 + j;
            v[j] = (k < IN_DIM) ? f2bf(xr[k]) : (short)0;
        }
    } else {
        #pragma unroll
        for (int j = 0; j < 8; ++j) v[j] = (short)0;
    }
    *(bf16x8*)(A + (size_t)m * KP1 + k0) = v;
}

// [Wl|Wr] (K x 256 each, row-major) -> Bt (512 x Kp bf16, N-major = B^T layout)
__global__ __launch_bounds__(256) void pack_w_kernel(const float* __restrict__ Wl,
                                                     const float* __restrict__ Wr,
                                                     short* __restrict__ Bt, int K, int Kp) {
    int idx = blockIdx.x * 256 + threadIdx.x;
    int perRow = Kp / 8;
    int n = idx / perRow;
    int t = idx - n * perRow;
    if (n >= 512) return;
    const float* W = (n < 256) ? Wl : Wr;
    int nc = n & 255;
    int k0 = t * 8;
    bf16x8 v;
    #pragma unroll
    for (int j = 0; j < 8; ++j) {
        int k = k0 + j;
        v[j] = (k < K) ? f2bf(W[(size_t)k * 256 + nc]) : (short)0;
    }
    *(bf16x8*)(Bt + (size_t)n * Kp + k0) = v;
}

// ---------------- bf16 MFMA GEMM (m97 structure), bf16 output ----------------
// C(M x 512 bf16) = A(MP x Kp) * Bt(512 x Kp)^T + bias ; 128x128 tile, 4 waves of 64x64
__global__ __launch_bounds__(256) void gemm_bf16_kernel(
    const short* __restrict__ A, const short* __restrict__ B,
    short* __restrict__ C,
    const float* __restrict__ biasLo, const float* __restrict__ biasHi,
    int Mstore, int Kp)
{
    __shared__ short As[128 * 32];
    __shared__ short Bs[128 * 32];
    const int tid  = threadIdx.x;
    const int wave = tid >> 6;
    const int lane = tid & 63;
    const int l15  = lane & 15;
    const int quad = lane >> 4;
    const int bm = blockIdx.x * 128;
    const int bn = blockIdx.y * 128;

    f32x4 acc[4][4] = {};

    const int srow = wave * 32 + (lane >> 2);
    const int scol = (lane & 3) * 8;
    const short* Ag0 = A + (size_t)(bm + srow) * Kp + scol;
    const short* Ag1 = Ag0 + (size_t)16 * Kp;
    const short* Bg0 = B + (size_t)(bn + srow) * Kp + scol;
    const short* Bg1 = Bg0 + (size_t)16 * Kp;
    short* As0 = &As[(wave * 32) * 32];
    short* As1 = &As[(wave * 32 + 16) * 32];
    short* Bs0 = &Bs[(wave * 32) * 32];
    short* Bs1 = &Bs[(wave * 32 + 16) * 32];

    const int wm = (wave & 1) * 64;
    const int wn = (wave >> 1) * 64;

    for (int kk = 0; kk < Kp; kk += 32) {
        async16(As0, Ag0 + kk);
        async16(As1, Ag1 + kk);
        async16(Bs0, Bg0 + kk);
        async16(Bs1, Bg1 + kk);
        __syncthreads();

        bf16x8 af[4], bfr[4];
        #pragma unroll
        for (int i = 0; i < 4; ++i)
            af[i] = *(const bf16x8*)&As[(wm + i * 16 + l15) * 32 + quad * 8];
        #pragma unroll
        for (int i = 0; i < 4; ++i)
            bfr[i] = *(const bf16x8*)&Bs[(wn + i * 16 + l15) * 32 + quad * 8];
        #pragma unroll
        for (int mi = 0; mi < 4; ++mi)
            #pragma unroll
            for (int ni = 0; ni < 4; ++ni)
                acc[mi][ni] = __builtin_amdgcn_mfma_f32_16x16x32_bf16(
                    af[mi], bfr[ni], acc[mi][ni], 0, 0, 0);
        __syncthreads();
    }

    // C/D layout: col = lane&15, row = quad*4 + reg  [measured m89/m91]
    #pragma unroll
    for (int mi = 0; mi < 4; ++mi) {
        int row = bm + wm + mi * 16 + quad * 4;
        #pragma unroll
        for (int ni = 0; ni < 4; ++ni) {
            int col = bn + wn + ni * 16 + l15;
            float bv = (col < 256) ? biasLo[col] : biasHi[col - 256];
            #pragma unroll
            for (int r = 0; r < 4; ++r) {
                int rr = row + r;
                if (rr < Mstore)
                    C[(size_t)rr * 512 + col] = f2bf(acc[mi][ni][r] + bv);
            }
        }
    }
}

// ---------------- CSR build (grouped by dst) ----------------
__global__ __launch_bounds__(256) void edge_count_kernel(const int* __restrict__ ei,
                                                         int* __restrict__ counts) {
    int e = blockIdx.x * 256 + threadIdx.x;
    if (e >= E_TOT) return;
    int dst = (e < N_EDGES) ? ei[N_EDGES + e] : (e - N_EDGES);
    atomicAdd(&counts[dst], 1);
}

// single block, 1024 threads x 32 nodes each; one barrier phase
__global__ __launch_bounds__(1024) void scan_kernel(const int* __restrict__ counts,
                                                    int* __restrict__ offs,
                                                    int* __restrict__ cursor) {
    __shared__ int wsum[16];
    int t = threadIdx.x;
    int lane = t & 63, wv = t >> 6;
    int base = t * 32;
    int local[32];
    int s = 0;
    #pragma unroll
    for (int j = 0; j < 32; ++j) {
        int i = base + j;
        int c = (i < N_NODES) ? counts[i] : 0;
        local[j] = s;
        s += c;
    }
    int incl = s;
    #pragma unroll
    for (int off = 1; off < 64; off <<= 1) {
        int v = __shfl_up(incl, off, 64);
        if (lane >= off) incl += v;
    }
    if (lane == 63) wsum[wv] = incl;
    __syncthreads();
    if (t == 0) {
        int run = 0;
        #pragma unroll
        for (int w2 = 0; w2 < 16; ++w2) { int v = wsum[w2]; wsum[w2] = run; run += v; }
        offs[N_NODES] = run;
    }
    __syncthreads();
    int thrExc = wsum[wv] + incl - s;
    #pragma unroll
    for (int j = 0; j < 32; ++j) {
        int i = base + j;
        if (i < N_NODES) {
            int o = thrExc + local[j];
            offs[i] = o;
            cursor[i] = o;
        }
    }
}

__global__ __launch_bounds__(256) void edge_scatter_kernel(const int* __restrict__ ei,
                                                           int* __restrict__ cursor,
                                                           int* __restrict__ srcs) {
    int e = blockIdx.x * 256 + threadIdx.x;
    if (e >= E_TOT) return;
    int src, dst;
    if (e < N_EDGES) { src = ei[e]; dst = ei[N_EDGES + e]; }
    else { src = e - N_EDGES; dst = src; }
    int pos = atomicAdd(&cursor[dst], 1);
    srcs[pos] = src;
}

// ---------------- layer-1 fused logits+softmax+aggregate ----------------
// one wave per dst node; lane l owns dims 4l..4l+3 (head = l>>4)
// exp without max-subtraction: |logit| <= ~4, exact in fp32
__global__ __launch_bounds__(256) void fused_aggr1_kernel(
    const int* __restrict__ offs, const int* __restrict__ srcs,
    const short* __restrict__ C, const float* __restrict__ att,
    const float* __restrict__ bias, short* __restrict__ h1b)
{
    int wid = (int)((blockIdx.x * 256 + threadIdx.x) >> 6);
    int lane = threadIdx.x & 63;
    if (wid >= N_NODES) return;
    int n = wid;
    int d0 = 4 * lane;
    float4 attv = *(const float4*)(att + d0);
    const short* crow = C + (size_t)n * 512 + 256 + d0;
    float xr0 = bf2f(crow[0]), xr1 = bf2f(crow[1]);
    float xr2 = bf2f(crow[2]), xr3 = bf2f(crow[3]);
    float a0 = 0.f, a1 = 0.f, a2 = 0.f, a3 = 0.f, den = 0.f;
    int beg = offs[n], end = offs[n + 1];
    for (int i = beg; i < end; ++i) {
        int s = srcs[i];
        short4v xl = *(const short4v*)(C + (size_t)s * 512 + d0);
        float x0 = bf2f(xl.x), x1 = bf2f(xl.y), x2 = bf2f(xl.z), x3 = bf2f(xl.w);
        float p = lrelu(x0 + xr0) * attv.x + lrelu(x1 + xr1) * attv.y
                + lrelu(x2 + xr2) * attv.z + lrelu(x3 + xr3) * attv.w;
        // reduce within the 16-lane head group (butterfly -> all lanes have sum)
        p += __shfl_xor(p, 1, 64);
        p += __shfl_xor(p, 2, 64);
        p += __shfl_xor(p, 4, 64);
        p += __shfl_xor(p, 8, 64);
        float wgt = __expf(p);
        den += wgt;
        a0 += wgt * x0; a1 += wgt * x1; a2 += wgt * x2; a3 += wgt * x3;
    }
    float inv = 1.f / (den + 1e-16f);
    float4 bv = *(const float4*)(bias + d0);
    short4v o;
    o.x = f2bf(elu1(a0 * inv + bv.x));
    o.y = f2bf(elu1(a1 * inv + bv.y));
    o.z = f2bf(elu1(a2 * inv + bv.z));
    o.w = f2bf(elu1(a3 * inv + bv.w));
    *(short4v*)(h1b + (size_t)n * 256 + d0) = o;
}

// ---------------- layer-2 fused (1 head x 256), f32 output ----------------
__global__ __launch_bounds__(256) void fused_aggr2_kernel(
    const int* __restrict__ offs, const int* __restrict__ srcs,
    const short* __restrict__ C, const float* __restrict__ att,
    const float* __restrict__ bias, float* __restrict__ h2)
{
    int wid = (int)((blockIdx.x * 256 + threadIdx.x) >> 6);
    int lane = threadIdx.x & 63;
    if (wid >= N_NODES) return;
    int n = wid;
    int d0 = 4 * lane;
    float4 attv = *(const float4*)(att + d0);
    const short* crow = C + (size_t)n * 512 + 256 + d0;
    float xr0 = bf2f(crow[0]), xr1 = bf2f(crow[1]);
    float xr2 = bf2f(crow[2]), xr3 = bf2f(crow[3]);
    float a0 = 0.f, a1 = 0.f, a2 = 0.f, a3 = 0.f, den = 0.f;
    int beg = offs[n], end = offs[n + 1];
    for (int i = beg; i < end; ++i) {
        int s = srcs[i];
        short4v xl = *(const short4v*)(C + (size_t)s * 512 + d0);
        float x0 = bf2f(xl.x), x1 = bf2f(xl.y), x2 = bf2f(xl.z), x3 = bf2f(xl.w);
        float p = lrelu(x0 + xr0) * attv.x + lrelu(x1 + xr1) * attv.y
                + lrelu(x2 + xr2) * attv.z + lrelu(x3 + xr3) * attv.w;
        // full 64-lane butterfly reduction
        p += __shfl_xor(p, 1, 64);
        p += __shfl_xor(p, 2, 64);
        p += __shfl_xor(p, 4, 64);
        p += __shfl_xor(p, 8, 64);
        p += __shfl_xor(p, 16, 64);
        p += __shfl_xor(p, 32, 64);
        float wgt = __expf(p);
        den += wgt;
        a0 += wgt * x0; a1 += wgt * x1; a2 += wgt * x2; a3 += wgt * x3;
    }
    float inv = 1.f / (den + 1e-16f);
    float4 bv = *(const float4*)(bias + d0);
    float4 o;
    o.x = elu1(a0 * inv + bv.x);
    o.y = elu1(a1 * inv + bv.y);
    o.z = elu1(a2 * inv + bv.z);
    o.w = elu1(a3 * inv + bv.w);
    *(float4*)(h2 + (size_t)n * 256 + d0) = o;
}

// ---------------- MLP head: one block (128 thr) per batch row ----------------
__global__ __launch_bounds__(128) void head_mlp_kernel(
    const float* __restrict__ h2, const int* __restrict__ sel,
    const float* __restrict__ wt, const float* __restrict__ mut,
    const float* __restrict__ W1, const float* __restrict__ b1,
    const float* __restrict__ W2, const float* __restrict__ b2,
    const float* __restrict__ W3, const float* __restrict__ b3,
    float* __restrict__ out)
{
    __shared__ float comb[296];
    __shared__ float z1[128];
    int b = blockIdx.x;
    int t = threadIdx.x;
    const float* hrow = h2 + (size_t)sel[b] * 256;
    comb[t] = hrow[t];
    comb[128 + t] = hrow[128 + t];
    if (t < 40) comb[256 + t] = (t < 20) ? wt[b * 20 + t] : mut[b * 20 + t - 20];
    __syncthreads();
    float s = b1[t];
    #pragma unroll 8
    for (int i = 0; i < 296; ++i) s += comb[i] * W1[i * 128 + t];
    z1[t] = fmaxf(s, 0.f);
    __syncthreads();
    if (t < 64) {
        float s2 = b2[t];
        #pragma unroll 8
        for (int i = 0; i < 128; ++i) s2 += z1[i] * W2[i * 64 + t];
        float v = fmaxf(s2, 0.f) * W3[t];
        #pragma unroll
        for (int off = 32; off > 0; off >>= 1) v += __shfl_xor(v, off, 64);
        if (t == 0) out[b] = v + b3[0];
    }
}

// ---------------- launch ----------------
extern "C" void kernel_launch(void* const* d_in, const int* in_sizes, int n_in,
                              void* d_out, int out_size, void* d_ws, size_t ws_size,
                              hipStream_t stream) {
    const float* x     = (const float*)d_in[0];
    const int*   ei    = (const int*)  d_in[1];
    const int*   sel   = (const int*)  d_in[2];
    const float* wt    = (const float*)d_in[3];
    const float* mut   = (const float*)d_in[4];
    const float* Wl1   = (const float*)d_in[5];
    const float* bl1   = (const float*)d_in[6];
    const float* Wr1   = (const float*)d_in[7];
    const float* br1   = (const float*)d_in[8];
    const float* att1  = (const float*)d_in[9];
    const float* bias1 = (const float*)d_in[10];
    const float* Wl2   = (const float*)d_in[11];
    const float* bl2   = (const float*)d_in[12];
    const float* Wr2   = (const float*)d_in[13];
    const float* br2   = (const float*)d_in[14];
    const float* att2  = (const float*)d_in[15];
    const float* bias2 = (const float*)d_in[16];
    const float* hW1   = (const float*)d_in[17];
    const float* hb1   = (const float*)d_in[18];
    const float* hW2   = (const float*)d_in[19];
    const float* hb2   = (const float*)d_in[20];
    const float* hW3   = (const float*)d_in[21];
    const float* hb3   = (const float*)d_in[22];
    float* out = (float*)d_out;

    // workspace layout (256B-aligned chunks)
    char* w = (char*)d_ws;
    size_t off = 0;
    auto alloc = [&](size_t bytes) -> void* {
        void* p = w + off;
        off += (bytes + 255) & ~(size_t)255;
        return p;
    };
    short* Abf    = (short*)alloc((size_t)MP * KP1 * 2);        // x bf16; later reused as C2 (bf16)
    short* Wbf    = (short*)alloc((size_t)512 * KP1 * 2);       // [Wl1|Wr1]^T bf16
    short* C1b    = (short*)alloc((size_t)N_NODES * 512 * 2);   // [xl1|xr1] bf16; later reused as h2 f32 (same bytes)
    int*   counts = (int*)  alloc((size_t)N_NODES * 4);
    int*   cursor = (int*)  alloc((size_t)N_NODES * 4);
    int*   offs   = (int*)  alloc((size_t)(N_NODES + 1) * 4);
    int*   srcs   = (int*)  alloc((size_t)E_TOT * 4);
    short* H1bf   = (short*)alloc((size_t)MP * 256 * 2);        // h1 bf16 (GEMM2 A)
    short* W2bf   = (short*)alloc((size_t)512 * 256 * 2);       // [Wl2|Wr2]^T bf16
    short* C2b = Abf;          // [xl2|xr2] bf16 overlays dead x-bf16 (30.7 MB < 79 MB)
    float* h2  = (float*)C1b;  // h2 f32 (30.7 MB) overlays dead C1b (30.7 MB)
    (void)in_sizes; (void)n_in; (void)out_size; (void)ws_size;

    hipMemsetAsync(counts, 0, (size_t)N_NODES * 4, stream);

    // pack inputs to bf16
    pack_x_kernel<<<(MP * (KP1 / 8)) / 256, 256, 0, stream>>>(x, Abf);
    pack_w_kernel<<<(512 * (KP1 / 8) + 255) / 256, 256, 0, stream>>>(Wl1, Wr1, Wbf, IN_DIM, KP1);
    pack_w_kernel<<<(512 * (256 / 8) + 255) / 256, 256, 0, stream>>>(Wl2, Wr2, W2bf, 256, 256);

    // CSR by dst (shared by both layers)
    edge_count_kernel<<<(E_TOT + 255) / 256, 256, 0, stream>>>(ei, counts);
    scan_kernel<<<1, 1024, 0, stream>>>(counts, offs, cursor);
    edge_scatter_kernel<<<(E_TOT + 255) / 256, 256, 0, stream>>>(ei, cursor, srcs);

    dim3 gemm_grid(MP / 128, 4);
    // layer 1
    gemm_bf16_kernel<<<gemm_grid, 256, 0, stream>>>(Abf, Wbf, C1b, bl1, br1, N_NODES, KP1);
    fused_aggr1_kernel<<<(N_NODES + 3) / 4, 256, 0, stream>>>(offs, srcs, C1b, att1, bias1, H1bf);
    // layer 2
    gemm_bf16_kernel<<<gemm_grid, 256, 0, stream>>>(H1bf, W2bf, C2b, bl2, br2, N_NODES, 256);
    fused_aggr2_kernel<<<(N_NODES + 3) / 4, 256, 0, stream>>>(offs, srcs, C2b, att2, bias2, h2);
    // head
    head_mlp_kernel<<<BQ, 128, 0, stream>>>(h2, sel, wt, mut, hW1, hb1, hW2, hb2, hW3, hb3, out);
}

// Round 3
// 691.509 us; speedup vs baseline: 1.5267x; 1.0421x over previous
//
#include <hip/hip_runtime.h>

// ---------------- problem constants ----------------
#define N_NODES 30000
#define N_EDGES 480000
#define E_TOT   510000        // edges + self loops
#define BQ      4096
#define IN_DIM  1281
#define KP1     1312          // 1281 padded to mult of 32
#define MP      30080         // 30000 padded to mult of 128

typedef __attribute__((ext_vector_type(8))) short bf16x8;
typedef __attribute__((ext_vector_type(4))) short short4v;
typedef __attribute__((ext_vector_type(4))) float f32x4;

__device__ __forceinline__ short f2bf(float f) {
    unsigned int u = __builtin_bit_cast(unsigned int, f);
    u += 0x7fffu + ((u >> 16) & 1u);       // RNE
    return (short)(u >> 16);
}

__device__ __forceinline__ float bf2f(short s) {
    unsigned int u = ((unsigned int)(unsigned short)s) << 16;
    return __builtin_bit_cast(float, u);
}

__device__ __forceinline__ void async16(void* lds, const void* g) {
    __builtin_amdgcn_global_load_lds(
        (const __attribute__((address_space(1))) void*)g,
        (__attribute__((address_space(3))) void*)lds, 16, 0, 0);
}

__device__ __forceinline__ float elu1(float x) {
    return x > 0.f ? x : __expf(x) - 1.f;
}

__device__ __forceinline__ float lrelu(float x) {
    return x > 0.f ? x : 0.2f * x;
}

// ---------------- pack kernels ----------------
// x (30000x1281 f32) -> A (30080x1312 bf16), zero padded.
// One block per destination row. Source rows are only 4B-aligned (1281 f32),
// so phase 1 uses lane-consecutive scalar dword loads (coalesced at any 4B
// alignment), bounces bf16 through LDS; phase 2 stores 16B-aligned dwordx4
// (dest row stride 2624B is 16B-aligned).
__global__ __launch_bounds__(256) void pack_x_kernel(const float* __restrict__ x,
                                                     short* __restrict__ A) {
    __shared__ short row[KP1];
    const int m = blockIdx.x;
    const int t = threadIdx.x;
    short* dst = A + (size_t)m * KP1;
    if (m >= N_NODES) {               // zero pad rows 30000..30079
        if (t < KP1 / 8) {
            bf16x8 z = {};
            *(bf16x8*)(dst + t * 8) = z;
        }
        return;
    }
    const float* src = x + (size_t)m * IN_DIM;
    for (int i = t; i < IN_DIM; i += 256) row[i] = f2bf(src[i]);
    if (t < KP1 - IN_DIM) row[IN_DIM + t] = 0;   // zero pad cols 1281..1311
    __syncthreads();
    if (t < KP1 / 8)
        *(bf16x8*)(dst + t * 8) = *(const bf16x8*)&row[t * 8];
}

// [Wl|Wr] (K x 256 each, row-major) -> Bt (512 x Kp bf16, N-major = B^T layout)
__global__ __launch_bounds__(256) void pack_w_kernel(const float* __restrict__ Wl,
                                                     const float* __restrict__ Wr,
                                                     short* __restrict__ Bt, int K, int Kp) {
    int idx = blockIdx.x * 256 + threadIdx.x;
    int perRow = Kp / 8;
    int n = idx / perRow;
    int t = idx - n * perRow;
    if (n >= 512) return;
    const float* W = (n < 256) ? Wl : Wr;
    int nc = n & 255;
    int k0 = t * 8;
    bf16x8 v;
    #pragma unroll
    for (int j = 0; j < 8; ++j) {
        int k = k0 + j;
        v[j] = (k < K) ? f2bf(W[(size_t)k * 256 + nc]) : (short)0;
    }
    *(bf16x8*)(Bt + (size_t)n * Kp + k0) = v;
}

// ---------------- bf16 MFMA GEMM (m97 structure), bf16 output ----------------
// C(M x 512 bf16) = A(MP x Kp) * Bt(512 x Kp)^T + bias ; 128x128 tile, 4 waves of 64x64
__global__ __launch_bounds__(256) void gemm_bf16_kernel(
    const short* __restrict__ A, const short* __restrict__ B,
    short* __restrict__ C,
    const float* __restrict__ biasLo, const float* __restrict__ biasHi,
    int Mstore, int Kp)
{
    __shared__ short As[128 * 32];
    __shared__ short Bs[128 * 32];
    const int tid  = threadIdx.x;
    const int wave = tid >> 6;
    const int lane = tid & 63;
    const int l15  = lane & 15;
    const int quad = lane >> 4;
    const int bm = blockIdx.x * 128;
    const int bn = blockIdx.y * 128;

    f32x4 acc[4][4] = {};

    const int srow = wave * 32 + (lane >> 2);
    const int scol = (lane & 3) * 8;
    const short* Ag0 = A + (size_t)(bm + srow) * Kp + scol;
    const short* Ag1 = Ag0 + (size_t)16 * Kp;
    const short* Bg0 = B + (size_t)(bn + srow) * Kp + scol;
    const short* Bg1 = Bg0 + (size_t)16 * Kp;
    short* As0 = &As[(wave * 32) * 32];
    short* As1 = &As[(wave * 32 + 16) * 32];
    short* Bs0 = &Bs[(wave * 32) * 32];
    short* Bs1 = &Bs[(wave * 32 + 16) * 32];

    const int wm = (wave & 1) * 64;
    const int wn = (wave >> 1) * 64;

    for (int kk = 0; kk < Kp; kk += 32) {
        async16(As0, Ag0 + kk);
        async16(As1, Ag1 + kk);
        async16(Bs0, Bg0 + kk);
        async16(Bs1, Bg1 + kk);
        __syncthreads();

        bf16x8 af[4], bfr[4];
        #pragma unroll
        for (int i = 0; i < 4; ++i)
            af[i] = *(const bf16x8*)&As[(wm + i * 16 + l15) * 32 + quad * 8];
        #pragma unroll
        for (int i = 0; i < 4; ++i)
            bfr[i] = *(const bf16x8*)&Bs[(wn + i * 16 + l15) * 32 + quad * 8];
        #pragma unroll
        for (int mi = 0; mi < 4; ++mi)
            #pragma unroll
            for (int ni = 0; ni < 4; ++ni)
                acc[mi][ni] = __builtin_amdgcn_mfma_f32_16x16x32_bf16(
                    af[mi], bfr[ni], acc[mi][ni], 0, 0, 0);
        __syncthreads();
    }

    // C/D layout: col = lane&15, row = quad*4 + reg  [measured m89/m91]
    #pragma unroll
    for (int mi = 0; mi < 4; ++mi) {
        int row = bm + wm + mi * 16 + quad * 4;
        #pragma unroll
        for (int ni = 0; ni < 4; ++ni) {
            int col = bn + wn + ni * 16 + l15;
            float bv = (col < 256) ? biasLo[col] : biasHi[col - 256];
            #pragma unroll
            for (int r = 0; r < 4; ++r) {
                int rr = row + r;
                if (rr < Mstore)
                    C[(size_t)rr * 512 + col] = f2bf(acc[mi][ni][r] + bv);
            }
        }
    }
}

// ---------------- CSR build (grouped by dst) ----------------
__global__ __launch_bounds__(256) void edge_count_kernel(const int* __restrict__ ei,
                                                         int* __restrict__ counts) {
    int e = blockIdx.x * 256 + threadIdx.x;
    if (e >= E_TOT) return;
    int dst = (e < N_EDGES) ? ei[N_EDGES + e] : (e - N_EDGES);
    atomicAdd(&counts[dst], 1);
}

// single block, 1024 threads x 32 nodes each; one barrier phase
__global__ __launch_bounds__(1024) void scan_kernel(const int* __restrict__ counts,
                                                    int* __restrict__ offs,
                                                    int* __restrict__ cursor) {
    __shared__ int wsum[16];
    int t = threadIdx.x;
    int lane = t & 63, wv = t >> 6;
    int base = t * 32;
    int local[32];
    int s = 0;
    #pragma unroll
    for (int j = 0; j < 32; ++j) {
        int i = base + j;
        int c = (i < N_NODES) ? counts[i] : 0;
        local[j] = s;
        s += c;
    }
    int incl = s;
    #pragma unroll
    for (int off = 1; off < 64; off <<= 1) {
        int v = __shfl_up(incl, off, 64);
        if (lane >= off) incl += v;
    }
    if (lane == 63) wsum[wv] = incl;
    __syncthreads();
    if (t == 0) {
        int run = 0;
        #pragma unroll
        for (int w2 = 0; w2 < 16; ++w2) { int v = wsum[w2]; wsum[w2] = run; run += v; }
        offs[N_NODES] = run;
    }
    __syncthreads();
    int thrExc = wsum[wv] + incl - s;
    #pragma unroll
    for (int j = 0; j < 32; ++j) {
        int i = base + j;
        if (i < N_NODES) {
            int o = thrExc + local[j];
            offs[i] = o;
            cursor[i] = o;
        }
    }
}

__global__ __launch_bounds__(256) void edge_scatter_kernel(const int* __restrict__ ei,
                                                           int* __restrict__ cursor,
                                                           int* __restrict__ srcs) {
    int e = blockIdx.x * 256 + threadIdx.x;
    if (e >= E_TOT) return;
    int src, dst;
    if (e < N_EDGES) { src = ei[e]; dst = ei[N_EDGES + e]; }
    else { src = e - N_EDGES; dst = src; }
    int pos = atomicAdd(&cursor[dst], 1);
    srcs[pos] = src;
}

// ---------------- layer-1 fused logits+softmax+aggregate ----------------
// one wave per dst node; lane l owns dims 4l..4l+3 (head = l>>4)
// exp without max-subtraction: |logit| <= ~4, exact in fp32
__global__ __launch_bounds__(256) void fused_aggr1_kernel(
    const int* __restrict__ offs, const int* __restrict__ srcs,
    const short* __restrict__ C, const float* __restrict__ att,
    const float* __restrict__ bias, short* __restrict__ h1b)
{
    int wid = (int)((blockIdx.x * 256 + threadIdx.x) >> 6);
    int lane = threadIdx.x & 63;
    if (wid >= N_NODES) return;
    int n = wid;
    int d0 = 4 * lane;
    float4 attv = *(const float4*)(att + d0);
    const short* crow = C + (size_t)n * 512 + 256 + d0;
    float xr0 = bf2f(crow[0]), xr1 = bf2f(crow[1]);
    float xr2 = bf2f(crow[2]), xr3 = bf2f(crow[3]);
    float a0 = 0.f, a1 = 0.f, a2 = 0.f, a3 = 0.f, den = 0.f;
    int beg = offs[n], end = offs[n + 1];
    for (int i = beg; i < end; ++i) {
        int s = srcs[i];
        short4v xl = *(const short4v*)(C + (size_t)s * 512 + d0);
        float x0 = bf2f(xl.x), x1 = bf2f(xl.y), x2 = bf2f(xl.z), x3 = bf2f(xl.w);
        float p = lrelu(x0 + xr0) * attv.x + lrelu(x1 + xr1) * attv.y
                + lrelu(x2 + xr2) * attv.z + lrelu(x3 + xr3) * attv.w;
        // reduce within the 16-lane head group (butterfly -> all lanes have sum)
        p += __shfl_xor(p, 1, 64);
        p += __shfl_xor(p, 2, 64);
        p += __shfl_xor(p, 4, 64);
        p += __shfl_xor(p, 8, 64);
        float wgt = __expf(p);
        den += wgt;
        a0 += wgt * x0; a1 += wgt * x1; a2 += wgt * x2; a3 += wgt * x3;
    }
    float inv = 1.f / (den + 1e-16f);
    float4 bv = *(const float4*)(bias + d0);
    short4v o;
    o.x = f2bf(elu1(a0 * inv + bv.x));
    o.y = f2bf(elu1(a1 * inv + bv.y));
    o.z = f2bf(elu1(a2 * inv + bv.z));
    o.w = f2bf(elu1(a3 * inv + bv.w));
    *(short4v*)(h1b + (size_t)n * 256 + d0) = o;
}

// ---------------- layer-2 fused (1 head x 256), f32 output ----------------
__global__ __launch_bounds__(256) void fused_aggr2_kernel(
    const int* __restrict__ offs, const int* __restrict__ srcs,
    const short* __restrict__ C, const float* __restrict__ att,
    const float* __restrict__ bias, float* __restrict__ h2)
{
    int wid = (int)((blockIdx.x * 256 + threadIdx.x) >> 6);
    int lane = threadIdx.x & 63;
    if (wid >= N_NODES) return;
    int n = wid;
    int d0 = 4 * lane;
    float4 attv = *(const float4*)(att + d0);
    const short* crow = C + (size_t)n * 512 + 256 + d0;
    float xr0 = bf2f(crow[0]), xr1 = bf2f(crow[1]);
    float xr2 = bf2f(crow[2]), xr3 = bf2f(crow[3]);
    float a0 = 0.f, a1 = 0.f, a2 = 0.f, a3 = 0.f, den = 0.f;
    int beg = offs[n], end = offs[n + 1];
    for (int i = beg; i < end; ++i) {
        int s = srcs[i];
        short4v xl = *(const short4v*)(C + (size_t)s * 512 + d0);
        float x0 = bf2f(xl.x), x1 = bf2f(xl.y), x2 = bf2f(xl.z), x3 = bf2f(xl.w);
        float p = lrelu(x0 + xr0) * attv.x + lrelu(x1 + xr1) * attv.y
                + lrelu(x2 + xr2) * attv.z + lrelu(x3 + xr3) * attv.w;
        // full 64-lane butterfly reduction
        p += __shfl_xor(p, 1, 64);
        p += __shfl_xor(p, 2, 64);
        p += __shfl_xor(p, 4, 64);
        p += __shfl_xor(p, 8, 64);
        p += __shfl_xor(p, 16, 64);
        p += __shfl_xor(p, 32, 64);
        float wgt = __expf(p);
        den += wgt;
        a0 += wgt * x0; a1 += wgt * x1; a2 += wgt * x2; a3 += wgt * x3;
    }
    float inv = 1.f / (den + 1e-16f);
    float4 bv = *(const float4*)(bias + d0);
    float4 o;
    o.x = elu1(a0 * inv + bv.x);
    o.y = elu1(a1 * inv + bv.y);
    o.z = elu1(a2 * inv + bv.z);
    o.w = elu1(a3 * inv + bv.w);
    *(float4*)(h2 + (size_t)n * 256 + d0) = o;
}

// ---------------- MLP head: one block (128 thr) per batch row ----------------
__global__ __launch_bounds__(128) void head_mlp_kernel(
    const float* __restrict__ h2, const int* __restrict__ sel,
    const float* __restrict__ wt, const float* __restrict__ mut,
    const float* __restrict__ W1, const float* __restrict__ b1,
    const float* __restrict__ W2, const float* __restrict__ b2,
    const float* __restrict__ W3, const float* __restrict__ b3,
    float* __restrict__ out)
{
    __shared__ float comb[296];
    __shared__ float z1[128];
    int b = blockIdx.x;
    int t = threadIdx.x;
    const float* hrow = h2 + (size_t)sel[b] * 256;
    comb[t] = hrow[t];
    comb[128 + t] = hrow[128 + t];
    if (t < 40) comb[256 + t] = (t < 20) ? wt[b * 20 + t] : mut[b * 20 + t - 20];
    __syncthreads();
    float s = b1[t];
    #pragma unroll 8
    for (int i = 0; i < 296; ++i) s += comb[i] * W1[i * 128 + t];
    z1[t] = fmaxf(s, 0.f);
    __syncthreads();
    if (t < 64) {
        float s2 = b2[t];
        #pragma unroll 8
        for (int i = 0; i < 128; ++i) s2 += z1[i] * W2[i * 64 + t];
        float v = fmaxf(s2, 0.f) * W3[t];
        #pragma unroll
        for (int off = 32; off > 0; off >>= 1) v += __shfl_xor(v, off, 64);
        if (t == 0) out[b] = v + b3[0];
    }
}

// ---------------- launch ----------------
extern "C" void kernel_launch(void* const* d_in, const int* in_sizes, int n_in,
                              void* d_out, int out_size, void* d_ws, size_t ws_size,
                              hipStream_t stream) {
    const float* x     = (const float*)d_in[0];
    const int*   ei    = (const int*)  d_in[1];
    const int*   sel   = (const int*)  d_in[2];
    const float* wt    = (const float*)d_in[3];
    const float* mut   = (const float*)d_in[4];
    const float* Wl1   = (const float*)d_in[5];
    const float* bl1   = (const float*)d_in[6];
    const float* Wr1   = (const float*)d_in[7];
    const float* br1   = (const float*)d_in[8];
    const float* att1  = (const float*)d_in[9];
    const float* bias1 = (const float*)d_in[10];
    const float* Wl2   = (const float*)d_in[11];
    const float* bl2   = (const float*)d_in[12];
    const float* Wr2   = (const float*)d_in[13];
    const float* br2   = (const float*)d_in[14];
    const float* att2  = (const float*)d_in[15];
    const float* bias2 = (const float*)d_in[16];
    const float* hW1   = (const float*)d_in[17];
    const float* hb1   = (const float*)d_in[18];
    const float* hW2   = (const float*)d_in[19];
    const float* hb2   = (const float*)d_in[20];
    const float* hW3   = (const float*)d_in[21];
    const float* hb3   = (const float*)d_in[22];
    float* out = (float*)d_out;

    // workspace layout (256B-aligned chunks)
    char* w = (char*)d_ws;
    size_t off = 0;
    auto alloc = [&](size_t bytes) -> void* {
        void* p = w + off;
        off += (bytes + 255) & ~(size_t)255;
        return p;
    };
    short* Abf    = (short*)alloc((size_t)MP * KP1 * 2);        // x bf16; later reused as C2 (bf16)
    short* Wbf    = (short*)alloc((size_t)512 * KP1 * 2);       // [Wl1|Wr1]^T bf16
    short* C1b    = (short*)alloc((size_t)N_NODES * 512 * 2);   // [xl1|xr1] bf16; later reused as h2 f32 (same bytes)
    int*   counts = (int*)  alloc((size_t)N_NODES * 4);
    int*   cursor = (int*)  alloc((size_t)N_NODES * 4);
    int*   offs   = (int*)  alloc((size_t)(N_NODES + 1) * 4);
    int*   srcs   = (int*)  alloc((size_t)E_TOT * 4);
    short* H1bf   = (short*)alloc((size_t)MP * 256 * 2);        // h1 bf16 (GEMM2 A)
    short* W2bf   = (short*)alloc((size_t)512 * 256 * 2);       // [Wl2|Wr2]^T bf16
    short* C2b = Abf;          // [xl2|xr2] bf16 overlays dead x-bf16 (30.7 MB < 79 MB)
    float* h2  = (float*)C1b;  // h2 f32 (30.7 MB) overlays dead C1b (30.7 MB)
    (void)in_sizes; (void)n_in; (void)out_size; (void)ws_size;

    hipMemsetAsync(counts, 0, (size_t)N_NODES * 4, stream);

    // pack inputs to bf16
    pack_x_kernel<<<MP, 256, 0, stream>>>(x, Abf);
    pack_w_kernel<<<(512 * (KP1 / 8) + 255) / 256, 256, 0, stream>>>(Wl1, Wr1, Wbf, IN_DIM, KP1);
    pack_w_kernel<<<(512 * (256 / 8) + 255) / 256, 256, 0, stream>>>(Wl2, Wr2, W2bf, 256, 256);

    // CSR by dst (shared by both layers)
    edge_count_kernel<<<(E_TOT + 255) / 256, 256, 0, stream>>>(ei, counts);
    scan_kernel<<<1, 1024, 0, stream>>>(counts, offs, cursor);
    edge_scatter_kernel<<<(E_TOT + 255) / 256, 256, 0, stream>>>(ei, cursor, srcs);

    dim3 gemm_grid(MP / 128, 4);
    // layer 1
    gemm_bf16_kernel<<<gemm_grid, 256, 0, stream>>>(Abf, Wbf, C1b, bl1, br1, N_NODES, KP1);
    fused_aggr1_kernel<<<(N_NODES + 3) / 4, 256, 0, stream>>>(offs, srcs, C1b, att1, bias1, H1bf);
    // layer 2
    gemm_bf16_kernel<<<gemm_grid, 256, 0, stream>>>(H1bf, W2bf, C2b, bl2, br2, N_NODES, 256);
    fused_aggr2_kernel<<<(N_NODES + 3) / 4, 256, 0, stream>>>(offs, srcs, C2b, att2, bias2, h2);
    // head
    head_mlp_kernel<<<BQ, 128, 0, stream>>>(h2, sel, wt, mut, hW1, hb1, hW2, hb2, hW3, hb3, out);
}

// Round 4
// 634.582 us; speedup vs baseline: 1.6637x; 1.0897x over previous
//
#include <hip/hip_runtime.h>

// ---------------- problem constants ----------------
#define N_NODES 30000
#define N_EDGES 480000
#define E_TOT   510000        // edges + self loops
#define BQ      4096
#define IN_DIM  1281
#define KP1     1312          // 1281 padded to mult of 32
#define MP      30080         // 30000 padded to mult of 128

typedef __attribute__((ext_vector_type(8))) short bf16x8;
typedef __attribute__((ext_vector_type(4))) short short4v;
typedef __attribute__((ext_vector_type(4))) float f32x4;

__device__ __forceinline__ short f2bf(float f) {
    unsigned int u = __builtin_bit_cast(unsigned int, f);
    u += 0x7fffu + ((u >> 16) & 1u);       // RNE
    return (short)(u >> 16);
}

__device__ __forceinline__ float bf2f(short s) {
    unsigned int u = ((unsigned int)(unsigned short)s) << 16;
    return __builtin_bit_cast(float, u);
}

__device__ __forceinline__ void async16(void* lds, const void* g) {
    __builtin_amdgcn_global_load_lds(
        (const __attribute__((address_space(1))) void*)g,
        (__attribute__((address_space(3))) void*)lds, 16, 0, 0);
}

__device__ __forceinline__ float elu1(float x) {
    return x > 0.f ? x : __expf(x) - 1.f;
}

__device__ __forceinline__ float lrelu(float x) {
    return x > 0.f ? x : 0.2f * x;
}

// ---------------- pack kernels ----------------
// x (30000x1281 f32) -> A (30080x1312 bf16), zero padded.
// One block per row; coalesced scalar dword loads -> LDS -> dwordx4 stores.
__global__ __launch_bounds__(256) void pack_x_kernel(const float* __restrict__ x,
                                                     short* __restrict__ A) {
    __shared__ short row[KP1];
    const int m = blockIdx.x;
    const int t = threadIdx.x;
    short* dst = A + (size_t)m * KP1;
    if (m >= N_NODES) {               // zero pad rows 30000..30079
        if (t < KP1 / 8) {
            bf16x8 z = {};
            *(bf16x8*)(dst + t * 8) = z;
        }
        return;
    }
    const float* src = x + (size_t)m * IN_DIM;
    for (int i = t; i < IN_DIM; i += 256) row[i] = f2bf(src[i]);
    if (t < KP1 - IN_DIM) row[IN_DIM + t] = 0;   // zero pad cols 1281..1311
    __syncthreads();
    if (t < KP1 / 8)
        *(bf16x8*)(dst + t * 8) = *(const bf16x8*)&row[t * 8];
}

// [Wl|Wr] (K x 256 each, row-major) -> Bt (512 x Kp bf16, N-major = B^T layout)
__global__ __launch_bounds__(256) void pack_w_kernel(const float* __restrict__ Wl,
                                                     const float* __restrict__ Wr,
                                                     short* __restrict__ Bt, int K, int Kp) {
    int idx = blockIdx.x * 256 + threadIdx.x;
    int perRow = Kp / 8;
    int n = idx / perRow;
    int t = idx - n * perRow;
    if (n >= 512) return;
    const float* W = (n < 256) ? Wl : Wr;
    int nc = n & 255;
    int k0 = t * 8;
    bf16x8 v;
    #pragma unroll
    for (int j = 0; j < 8; ++j) {
        int k = k0 + j;
        v[j] = (k < K) ? f2bf(W[(size_t)k * 256 + nc]) : (short)0;
    }
    *(bf16x8*)(Bt + (size_t)n * Kp + k0) = v;
}

// ---------------- bf16 MFMA GEMM, 64x128 tile, XOR-swizzled LDS ----------------
// C(M x 512 bf16) = A(MP x Kp) * Bt(512 x Kp)^T + bias
// grid (4 bn-columns, MP/64 bm-rows): x-fastest => 4 blocks sharing an A-tile
// dispatch adjacently (A read once from HBM, 3x from L2/L3).
// LDS chunk layout: LDS(r,c) = data(r, c ^ ((r>>2)&3)) -- staged by permuting
// each lane's global source column (glds lane->LDS mapping is fixed-contiguous).
// Fragment reads then spread 16 lanes over 8 distinct 4-bank windows, 2 lanes
// each: 2-way aliasing is free [m136].
__global__ __launch_bounds__(256) void gemm_bf16_kernel(
    const short* __restrict__ A, const short* __restrict__ B,
    short* __restrict__ C,
    const float* __restrict__ biasLo, const float* __restrict__ biasHi,
    int Mstore, int Kp)
{
    __shared__ short As[64 * 32];     // 4 KB
    __shared__ short Bs[128 * 32];    // 8 KB
    const int tid  = threadIdx.x;
    const int wave = tid >> 6;
    const int lane = tid & 63;
    const int l15  = lane & 15;
    const int quad = lane >> 4;
    const int bn = blockIdx.x * 128;
    const int bm = blockIdx.y * 64;

    f32x4 acc[2][4] = {};

    // staging source: lane = r_local*4 + q ; source chunk col = q ^ ((r_local>>2)&3)
    const int r_local = lane >> 2;
    const int csrc = (lane & 3) ^ ((r_local >> 2) & 3);
    const short* Ag  = A + (size_t)(bm + 16 * wave + r_local) * Kp + csrc * 8;
    const short* Bg0 = B + (size_t)(bn + 32 * wave + r_local) * Kp + csrc * 8;
    const short* Bg1 = Bg0 + (size_t)16 * Kp;
    short* AsW  = &As[(16 * wave) * 32];
    short* BsW0 = &Bs[(32 * wave) * 32];
    short* BsW1 = &Bs[(32 * wave + 16) * 32];

    const int wm = (wave & 1) * 32;   // wave tile 32x64
    const int wn = (wave >> 1) * 64;
    const int xorT = (l15 >> 2) & 3;  // read-side swizzle term

    for (int kk = 0; kk < Kp; kk += 32) {
        async16(AsW,  Ag  + kk);
        async16(BsW0, Bg0 + kk);
        async16(BsW1, Bg1 + kk);
        __syncthreads();

        bf16x8 af[2], bfr[4];
        #pragma unroll
        for (int i = 0; i < 2; ++i)
            af[i] = *(const bf16x8*)&As[(wm + i * 16 + l15) * 32 + ((quad ^ xorT)) * 8];
        #pragma unroll
        for (int i = 0; i < 4; ++i)
            bfr[i] = *(const bf16x8*)&Bs[(wn + i * 16 + l15) * 32 + ((quad ^ xorT)) * 8];
        #pragma unroll
        for (int mi = 0; mi < 2; ++mi)
            #pragma unroll
            for (int ni = 0; ni < 4; ++ni)
                acc[mi][ni] = __builtin_amdgcn_mfma_f32_16x16x32_bf16(
                    af[mi], bfr[ni], acc[mi][ni], 0, 0, 0);
        __syncthreads();
    }

    // C/D layout: col = lane&15, row = quad*4 + reg  [measured m89/m91]
    #pragma unroll
    for (int mi = 0; mi < 2; ++mi) {
        int row = bm + wm + mi * 16 + quad * 4;
        #pragma unroll
        for (int ni = 0; ni < 4; ++ni) {
            int col = bn + wn + ni * 16 + l15;
            float bv = (col < 256) ? biasLo[col] : biasHi[col - 256];
            #pragma unroll
            for (int r = 0; r < 4; ++r) {
                int rr = row + r;
                if (rr < Mstore)
                    C[(size_t)rr * 512 + col] = f2bf(acc[mi][ni][r] + bv);
            }
        }
    }
}

// ---------------- CSR build (grouped by dst) ----------------
__global__ __launch_bounds__(256) void edge_count_kernel(const int* __restrict__ ei,
                                                         int* __restrict__ counts) {
    int e = blockIdx.x * 256 + threadIdx.x;
    if (e >= E_TOT) return;
    int dst = (e < N_EDGES) ? ei[N_EDGES + e] : (e - N_EDGES);
    atomicAdd(&counts[dst], 1);
}

// single block, 1024 threads x 32 nodes each; one barrier phase
__global__ __launch_bounds__(1024) void scan_kernel(const int* __restrict__ counts,
                                                    int* __restrict__ offs,
                                                    int* __restrict__ cursor) {
    __shared__ int wsum[16];
    int t = threadIdx.x;
    int lane = t & 63, wv = t >> 6;
    int base = t * 32;
    int local[32];
    int s = 0;
    #pragma unroll
    for (int j = 0; j < 32; ++j) {
        int i = base + j;
        int c = (i < N_NODES) ? counts[i] : 0;
        local[j] = s;
        s += c;
    }
    int incl = s;
    #pragma unroll
    for (int off = 1; off < 64; off <<= 1) {
        int v = __shfl_up(incl, off, 64);
        if (lane >= off) incl += v;
    }
    if (lane == 63) wsum[wv] = incl;
    __syncthreads();
    if (t == 0) {
        int run = 0;
        #pragma unroll
        for (int w2 = 0; w2 < 16; ++w2) { int v = wsum[w2]; wsum[w2] = run; run += v; }
        offs[N_NODES] = run;
    }
    __syncthreads();
    int thrExc = wsum[wv] + incl - s;
    #pragma unroll
    for (int j = 0; j < 32; ++j) {
        int i = base + j;
        if (i < N_NODES) {
            int o = thrExc + local[j];
            offs[i] = o;
            cursor[i] = o;
        }
    }
}

__global__ __launch_bounds__(256) void edge_scatter_kernel(const int* __restrict__ ei,
                                                           int* __restrict__ cursor,
                                                           int* __restrict__ srcs) {
    int e = blockIdx.x * 256 + threadIdx.x;
    if (e >= E_TOT) return;
    int src, dst;
    if (e < N_EDGES) { src = ei[e]; dst = ei[N_EDGES + e]; }
    else { src = e - N_EDGES; dst = src; }
    int pos = atomicAdd(&cursor[dst], 1);
    srcs[pos] = src;
}

// ---------------- layer-1 fused logits+softmax+aggregate ----------------
// one wave per dst node, TWO edges per iteration: lanes 0-31 edge i, lanes
// 32-63 edge i+1. Lane owns 8 dims (16B gathers); head = (lane&31)>>3.
// exp without max-subtraction: |logit| <= ~4, exact in fp32.
__global__ __launch_bounds__(256) void fused_aggr1_kernel(
    const int* __restrict__ offs, const int* __restrict__ srcs,
    const short* __restrict__ C, const float* __restrict__ att,
    const float* __restrict__ bias, short* __restrict__ h1b)
{
    int wid = (int)((blockIdx.x * 256 + threadIdx.x) >> 6);
    int lane = threadIdx.x & 63;
    if (wid >= N_NODES) return;
    int n = wid;
    int half = lane >> 5;
    int l5 = lane & 31;
    int d0 = l5 * 8;
    float attv[8], xr[8];
    {
        float4 aa = *(const float4*)(att + d0);
        float4 ab = *(const float4*)(att + d0 + 4);
        attv[0]=aa.x; attv[1]=aa.y; attv[2]=aa.z; attv[3]=aa.w;
        attv[4]=ab.x; attv[5]=ab.y; attv[6]=ab.z; attv[7]=ab.w;
        bf16x8 xv = *(const bf16x8*)(C + (size_t)n * 512 + 256 + d0);
        #pragma unroll
        for (int j = 0; j < 8; ++j) xr[j] = bf2f(xv[j]);
    }
    float a[8] = {};
    float den = 0.f;
    int beg = offs[n], end = offs[n + 1];
    for (int i = beg; i < end; i += 2) {
        int idx = i + half;
        bool act = idx < end;
        int s = srcs[act ? idx : (end - 1)];
        bf16x8 xlv = *(const bf16x8*)(C + (size_t)s * 512 + d0);
        float xl[8];
        #pragma unroll
        for (int j = 0; j < 8; ++j) xl[j] = bf2f(xlv[j]);
        float p = 0.f;
        #pragma unroll
        for (int j = 0; j < 8; ++j) p += lrelu(xl[j] + xr[j]) * attv[j];
        // reduce within the 8-lane head group
        p += __shfl_xor(p, 1, 64);
        p += __shfl_xor(p, 2, 64);
        p += __shfl_xor(p, 4, 64);
        float wgt = act ? __expf(p) : 0.f;
        den += wgt;
        #pragma unroll
        for (int j = 0; j < 8; ++j) a[j] += wgt * xl[j];
    }
    // combine the two half-wave edge subsets
    den += __shfl_xor(den, 32, 64);
    #pragma unroll
    for (int j = 0; j < 8; ++j) a[j] += __shfl_xor(a[j], 32, 64);
    if (half == 0) {
        float inv = 1.f / (den + 1e-16f);
        bf16x8 o;
        #pragma unroll
        for (int j = 0; j < 8; ++j) o[j] = f2bf(elu1(a[j] * inv + bias[d0 + j]));
        *(bf16x8*)(h1b + (size_t)n * 256 + d0) = o;
    }
}

// ---------------- layer-2 fused (1 head x 256), f32 output ----------------
__global__ __launch_bounds__(256) void fused_aggr2_kernel(
    const int* __restrict__ offs, const int* __restrict__ srcs,
    const short* __restrict__ C, const float* __restrict__ att,
    const float* __restrict__ bias, float* __restrict__ h2)
{
    int wid = (int)((blockIdx.x * 256 + threadIdx.x) >> 6);
    int lane = threadIdx.x & 63;
    if (wid >= N_NODES) return;
    int n = wid;
    int half = lane >> 5;
    int l5 = lane & 31;
    int d0 = l5 * 8;
    float attv[8], xr[8];
    {
        float4 aa = *(const float4*)(att + d0);
        float4 ab = *(const float4*)(att + d0 + 4);
        attv[0]=aa.x; attv[1]=aa.y; attv[2]=aa.z; attv[3]=aa.w;
        attv[4]=ab.x; attv[5]=ab.y; attv[6]=ab.z; attv[7]=ab.w;
        bf16x8 xv = *(const bf16x8*)(C + (size_t)n * 512 + 256 + d0);
        #pragma unroll
        for (int j = 0; j < 8; ++j) xr[j] = bf2f(xv[j]);
    }
    float a[8] = {};
    float den = 0.f;
    int beg = offs[n], end = offs[n + 1];
    for (int i = beg; i < end; i += 2) {
        int idx = i + half;
        bool act = idx < end;
        int s = srcs[act ? idx : (end - 1)];
        bf16x8 xlv = *(const bf16x8*)(C + (size_t)s * 512 + d0);
        float xl[8];
        #pragma unroll
        for (int j = 0; j < 8; ++j) xl[j] = bf2f(xlv[j]);
        float p = 0.f;
        #pragma unroll
        for (int j = 0; j < 8; ++j) p += lrelu(xl[j] + xr[j]) * attv[j];
        // reduce over the 32-lane half-wave (single head = 256 dims)
        p += __shfl_xor(p, 1, 64);
        p += __shfl_xor(p, 2, 64);
        p += __shfl_xor(p, 4, 64);
        p += __shfl_xor(p, 8, 64);
        p += __shfl_xor(p, 16, 64);
        float wgt = act ? __expf(p) : 0.f;
        den += wgt;
        #pragma unroll
        for (int j = 0; j < 8; ++j) a[j] += wgt * xl[j];
    }
    den += __shfl_xor(den, 32, 64);
    #pragma unroll
    for (int j = 0; j < 8; ++j) a[j] += __shfl_xor(a[j], 32, 64);
    if (half == 0) {
        float inv = 1.f / (den + 1e-16f);
        float4 o0, o1;
        o0.x = elu1(a[0] * inv + bias[d0 + 0]);
        o0.y = elu1(a[1] * inv + bias[d0 + 1]);
        o0.z = elu1(a[2] * inv + bias[d0 + 2]);
        o0.w = elu1(a[3] * inv + bias[d0 + 3]);
        o1.x = elu1(a[4] * inv + bias[d0 + 4]);
        o1.y = elu1(a[5] * inv + bias[d0 + 5]);
        o1.z = elu1(a[6] * inv + bias[d0 + 6]);
        o1.w = elu1(a[7] * inv + bias[d0 + 7]);
        *(float4*)(h2 + (size_t)n * 256 + d0) = o0;
        *(float4*)(h2 + (size_t)n * 256 + d0 + 4) = o1;
    }
}

// ---------------- MLP head: one block (128 thr) per batch row ----------------
__global__ __launch_bounds__(128) void head_mlp_kernel(
    const float* __restrict__ h2, const int* __restrict__ sel,
    const float* __restrict__ wt, const float* __restrict__ mut,
    const float* __restrict__ W1, const float* __restrict__ b1,
    const float* __restrict__ W2, const float* __restrict__ b2,
    const float* __restrict__ W3, const float* __restrict__ b3,
    float* __restrict__ out)
{
    __shared__ float comb[296];
    __shared__ float z1[128];
    int b = blockIdx.x;
    int t = threadIdx.x;
    const float* hrow = h2 + (size_t)sel[b] * 256;
    comb[t] = hrow[t];
    comb[128 + t] = hrow[128 + t];
    if (t < 40) comb[256 + t] = (t < 20) ? wt[b * 20 + t] : mut[b * 20 + t - 20];
    __syncthreads();
    float s = b1[t];
    #pragma unroll 8
    for (int i = 0; i < 296; ++i) s += comb[i] * W1[i * 128 + t];
    z1[t] = fmaxf(s, 0.f);
    __syncthreads();
    if (t < 64) {
        float s2 = b2[t];
        #pragma unroll 8
        for (int i = 0; i < 128; ++i) s2 += z1[i] * W2[i * 64 + t];
        float v = fmaxf(s2, 0.f) * W3[t];
        #pragma unroll
        for (int off = 32; off > 0; off >>= 1) v += __shfl_xor(v, off, 64);
        if (t == 0) out[b] = v + b3[0];
    }
}

// ---------------- launch ----------------
extern "C" void kernel_launch(void* const* d_in, const int* in_sizes, int n_in,
                              void* d_out, int out_size, void* d_ws, size_t ws_size,
                              hipStream_t stream) {
    const float* x     = (const float*)d_in[0];
    const int*   ei    = (const int*)  d_in[1];
    const int*   sel   = (const int*)  d_in[2];
    const float* wt    = (const float*)d_in[3];
    const float* mut   = (const float*)d_in[4];
    const float* Wl1   = (const float*)d_in[5];
    const float* bl1   = (const float*)d_in[6];
    const float* Wr1   = (const float*)d_in[7];
    const float* br1   = (const float*)d_in[8];
    const float* att1  = (const float*)d_in[9];
    const float* bias1 = (const float*)d_in[10];
    const float* Wl2   = (const float*)d_in[11];
    const float* bl2   = (const float*)d_in[12];
    const float* Wr2   = (const float*)d_in[13];
    const float* br2   = (const float*)d_in[14];
    const float* att2  = (const float*)d_in[15];
    const float* bias2 = (const float*)d_in[16];
    const float* hW1   = (const float*)d_in[17];
    const float* hb1   = (const float*)d_in[18];
    const float* hW2   = (const float*)d_in[19];
    const float* hb2   = (const float*)d_in[20];
    const float* hW3   = (const float*)d_in[21];
    const float* hb3   = (const float*)d_in[22];
    float* out = (float*)d_out;

    // workspace layout (256B-aligned chunks)
    char* w = (char*)d_ws;
    size_t off = 0;
    auto alloc = [&](size_t bytes) -> void* {
        void* p = w + off;
        off += (bytes + 255) & ~(size_t)255;
        return p;
    };
    short* Abf    = (short*)alloc((size_t)MP * KP1 * 2);        // x bf16; later reused as C2 (bf16)
    short* Wbf    = (short*)alloc((size_t)512 * KP1 * 2);       // [Wl1|Wr1]^T bf16
    short* C1b    = (short*)alloc((size_t)N_NODES * 512 * 2);   // [xl1|xr1] bf16; later reused as h2 f32
    int*   counts = (int*)  alloc((size_t)N_NODES * 4);
    int*   cursor = (int*)  alloc((size_t)N_NODES * 4);
    int*   offs   = (int*)  alloc((size_t)(N_NODES + 1) * 4);
    int*   srcs   = (int*)  alloc((size_t)E_TOT * 4);
    short* H1bf   = (short*)alloc((size_t)MP * 256 * 2);        // h1 bf16 (GEMM2 A)
    short* W2bf   = (short*)alloc((size_t)512 * 256 * 2);       // [Wl2|Wr2]^T bf16
    short* C2b = Abf;          // [xl2|xr2] bf16 overlays dead x-bf16
    float* h2  = (float*)C1b;  // h2 f32 overlays dead C1b
    (void)in_sizes; (void)n_in; (void)out_size; (void)ws_size;

    hipMemsetAsync(counts, 0, (size_t)N_NODES * 4, stream);

    // pack inputs to bf16
    pack_x_kernel<<<MP, 256, 0, stream>>>(x, Abf);
    pack_w_kernel<<<(512 * (KP1 / 8) + 255) / 256, 256, 0, stream>>>(Wl1, Wr1, Wbf, IN_DIM, KP1);
    pack_w_kernel<<<(512 * (256 / 8) + 255) / 256, 256, 0, stream>>>(Wl2, Wr2, W2bf, 256, 256);

    // CSR by dst (shared by both layers)
    edge_count_kernel<<<(E_TOT + 255) / 256, 256, 0, stream>>>(ei, counts);
    scan_kernel<<<1, 1024, 0, stream>>>(counts, offs, cursor);
    edge_scatter_kernel<<<(E_TOT + 255) / 256, 256, 0, stream>>>(ei, cursor, srcs);

    dim3 gemm_grid(4, MP / 64);   // x = bn column (fast), y = bm row -> A-tile L2/L3 reuse
    // layer 1
    gemm_bf16_kernel<<<gemm_grid, 256, 0, stream>>>(Abf, Wbf, C1b, bl1, br1, N_NODES, KP1);
    fused_aggr1_kernel<<<(N_NODES + 3) / 4, 256, 0, stream>>>(offs, srcs, C1b, att1, bias1, H1bf);
    // layer 2
    gemm_bf16_kernel<<<gemm_grid, 256, 0, stream>>>(H1bf, W2bf, C2b, bl2, br2, N_NODES, 256);
    fused_aggr2_kernel<<<(N_NODES + 3) / 4, 256, 0, stream>>>(offs, srcs, C2b, att2, bias2, h2);
    // head
    head_mlp_kernel<<<BQ, 128, 0, stream>>>(h2, sel, wt, mut, hW1, hb1, hW2, hb2, hW3, hb3, out);
}